// Round 6
// baseline (1408.363 us; speedup 1.0000x reference)
//
#include <hip/hip_runtime.h>

typedef short v8s __attribute__((ext_vector_type(8)));
typedef float v4f __attribute__((ext_vector_type(4)));
typedef float v32f __attribute__((ext_vector_type(32)));

__device__ __forceinline__ unsigned short f2bf(float f){
  unsigned u = __builtin_bit_cast(unsigned, f);
  return (unsigned short)((u + 0x7fffu + ((u>>16)&1u)) >> 16);
}
__device__ __forceinline__ float bf2f(unsigned short s){
  return __builtin_bit_cast(float, ((unsigned)s) << 16);
}

// -------- conv1x1 as MFMA GEMM, both tensors in one launch.
// Q/K out-channels (0..191) -> Sqk (in d_out); V out-channels (192..383) -> Sv (in ws).
// grid 4096 (2 tensors x 2048 n-tiles of 64), block 512 (8 waves, m-stripes of 48).
__global__ __launch_bounds__(512) void k_conv1x1(
    const float* __restrict__ hsi, const float* __restrict__ lidar,
    const unsigned short* __restrict__ Wfrag, const float* __restrict__ hqb,
    const float* __restrict__ lkb, unsigned short* __restrict__ Sqk,
    unsigned short* __restrict__ Sv)
{
  const int bx   = blockIdx.x;
  const int tens = bx >> 11;
  const int nt   = bx & 2047;
  const int b    = nt >> 8;
  const int hw0  = (nt & 255) << 6;
  const float* X = (tens ? lidar : hsi) + ((size_t)b * 192) * 16384 + hw0;
  const float* bias = tens ? lkb : hqb;

  __shared__ unsigned short Xt[64][200];   // transposed bf16 X tile, padded

  // stage: thread t -> cols c4..c4+3, rows {2*krow, 2*krow+1} + 64j
  {
    const int c4   = (threadIdx.x & 15) * 4;
    const int krow = threadIdx.x >> 4;     // 0..31
    const float* xb2 = X + c4;
    float4 f[6];
    #pragma unroll
    for (int j = 0; j < 3; ++j){
      const int k = krow*2 + j*64;
      f[2*j]   = *(const float4*)(xb2 + (size_t)k * 16384);
      f[2*j+1] = *(const float4*)(xb2 + (size_t)(k+1) * 16384);
    }
    #pragma unroll
    for (int j = 0; j < 3; ++j){
      const int k = krow*2 + j*64;
      #pragma unroll
      for (int i2 = 0; i2 < 4; ++i2){
        const unsigned lo = f2bf(((const float*)&f[2*j])[i2]);
        const unsigned hi = f2bf(((const float*)&f[2*j+1])[i2]);
        *(unsigned*)&Xt[c4 + i2][k] = lo | (hi << 16);
      }
    }
  }
  __syncthreads();

  const int lane = threadIdx.x & 63;
  const int wid  = threadIdx.x >> 6;      // 0..7
  const int l15  = lane & 15;
  const int g    = lane >> 4;
  const int mstripe = wid * 48;
  const unsigned short* wb = Wfrag + ((size_t)(tens*8 + wid) * 18) * 512 + (lane << 3);

  v4f acc[3][4];
  #pragma unroll
  for (int i=0;i<3;i++)
    #pragma unroll
    for (int j=0;j<4;j++)
      acc[i][j] = (v4f){0.f,0.f,0.f,0.f};

  #pragma unroll
  for (int ks=0; ks<6; ++ks){
    const int k0 = ks*32;
    v8s af[3];
    #pragma unroll
    for (int mi=0; mi<3; ++mi)
      af[mi] = *(const v8s*)(wb + (size_t)(ks*3 + mi) * 512);
    #pragma unroll
    for (int ni=0; ni<4; ++ni){
      const v8s bfr = *(const v8s*)&Xt[ni*16 + l15][k0 + 8*g];
      #pragma unroll
      for (int mi=0; mi<3; ++mi)
        acc[mi][ni] = __builtin_amdgcn_mfma_f32_16x16x32_bf16(af[mi], bfr, acc[mi][ni], 0, 0, 0);
    }
  }

  // epilogue: waves 0-3 -> Sqk (c 0..191), waves 4-7 -> Sv (c-192)
  unsigned short* outp;
  int cb;
  if (mstripe < 192){
    outp = Sqk + ((size_t)(tens*8 + b) * 192) * 16384 + hw0;
    cb = mstripe;
  } else {
    outp = Sv + ((size_t)(tens*8 + b) * 192) * 16384 + hw0;
    cb = mstripe - 192;
  }
  #pragma unroll
  for (int mi=0; mi<3; ++mi){
    #pragma unroll
    for (int r=0; r<4; ++r){
      const int co = mi*16 + 4*g + r;
      const float bs = bias[mstripe + co];
      #pragma unroll
      for (int ni=0; ni<4; ++ni)
        outp[(size_t)(cb + co)*16384 + ni*16 + l15] = f2bf(acc[mi][ni][r] + bs);
    }
  }
}

// -------- depthwise 3x3 SAME, Q/K halves only. one thread = 8 outputs along w.
// grid 24576, block 256. pc = plane (tens*1536 + b*192 + c), c in [0,192)
__global__ __launch_bounds__(256) void k_dw(
    const unsigned short* __restrict__ Sqk, const float* __restrict__ hdw,
    const float* __restrict__ ldw, const float* __restrict__ hdb,
    const float* __restrict__ ldb, unsigned short* __restrict__ Qh,
    unsigned short* __restrict__ Kl)
{
  const int idx = blockIdx.x*256 + threadIdx.x;
  const int w8 = idx & 15;
  const int h  = (idx >> 4) & 127;
  const int pc = idx >> 11;            // 0..3071
  const int tens = (pc >= 1536);
  const int lc = pc - tens*1536;       // b*192 + c
  const int c  = lc % 192;
  const unsigned short* in = Sqk + (size_t)pc*16384;

  float r[3][10];
  #pragma unroll
  for (int dy=0; dy<3; ++dy){
    const int hh = h + dy - 1;
    if (hh >= 0 && hh < 128){
      const unsigned short* row = in + hh*128 + w8*8;
      const v8s m = *(const v8s*)row;
      #pragma unroll
      for (int i=0;i<8;++i) r[dy][i+1] = bf2f((unsigned short)m[i]);
      r[dy][0] = (w8 > 0)  ? bf2f(row[-1]) : 0.f;
      r[dy][9] = (w8 < 15) ? bf2f(row[8])  : 0.f;
    } else {
      #pragma unroll
      for (int i=0;i<10;++i) r[dy][i] = 0.f;
    }
  }
  const float* wp = (tens ? ldw : hdw) + c*9;
  const float k00=wp[0],k01=wp[1],k02=wp[2],k10=wp[3],k11=wp[4],k12=wp[5],k20=wp[6],k21=wp[7],k22=wp[8];
  const float bs = (tens ? ldb : hdb)[c];
  v8s out;
  #pragma unroll
  for (int j=0;j<8;++j){
    float a = bs
      + r[0][j]*k00 + r[0][j+1]*k01 + r[0][j+2]*k02
      + r[1][j]*k10 + r[1][j+1]*k11 + r[1][j+2]*k12
      + r[2][j]*k20 + r[2][j+1]*k21 + r[2][j+2]*k22;
    out[j] = (short)f2bf(a);
  }
  *(v8s*)((tens ? Kl : Qh) + (size_t)lc*16384 + h*128 + w8*8) = out;
}

// -------- QK^T partials + row sumsq via Gram MFMAs.
// grid (48, 16), block 256 (4 waves, 256 s each). P: [48][64][1088]
__global__ __launch_bounds__(256) void k_qk(
    const unsigned short* __restrict__ Q, const unsigned short* __restrict__ K,
    float* __restrict__ P)
{
  const int bh = blockIdx.x, split = blockIdx.y;
  const int lane = threadIdx.x & 63, wid = threadIdx.x >> 6;
  const int l15 = lane & 15, g = lane >> 4;
  const int b = bh/6, hd = bh%6;
  const unsigned short* qb = Q + ((size_t)b*192 + hd*32)*16384;
  const unsigned short* kb = K + ((size_t)b*192 + hd*32)*16384;
  const int s0 = (split*4 + wid)*256;

  v4f aqk[2][2], aqq[2], akk[2];
  #pragma unroll
  for (int i=0;i<2;i++){
    aqq[i] = (v4f){0.f,0.f,0.f,0.f};
    akk[i] = (v4f){0.f,0.f,0.f,0.f};
    #pragma unroll
    for (int j=0;j<2;j++) aqk[i][j] = (v4f){0.f,0.f,0.f,0.f};
  }

  #pragma unroll
  for (int ks=0; ks<8; ++ks){
    const int s = s0 + ks*32 + 8*g;
    v8s qf[2], kf[2];
    #pragma unroll
    for (int mi=0;mi<2;++mi) qf[mi] = *(const v8s*)(qb + (size_t)(mi*16 + l15)*16384 + s);
    #pragma unroll
    for (int ni=0;ni<2;++ni) kf[ni] = *(const v8s*)(kb + (size_t)(ni*16 + l15)*16384 + s);
    #pragma unroll
    for (int mi=0;mi<2;++mi)
      #pragma unroll
      for (int ni=0;ni<2;++ni)
        aqk[mi][ni] = __builtin_amdgcn_mfma_f32_16x16x32_bf16(qf[mi], kf[ni], aqk[mi][ni],0,0,0);
    #pragma unroll
    for (int mi=0;mi<2;++mi){
      aqq[mi] = __builtin_amdgcn_mfma_f32_16x16x32_bf16(qf[mi], qf[mi], aqq[mi],0,0,0);
      akk[mi] = __builtin_amdgcn_mfma_f32_16x16x32_bf16(kf[mi], kf[mi], akk[mi],0,0,0);
    }
  }
  float* slot = P + ((size_t)bh*64 + split*4 + wid)*1088;
  #pragma unroll
  for (int mi=0;mi<2;++mi)
    #pragma unroll
    for (int ni=0;ni<2;++ni)
      #pragma unroll
      for (int r=0;r<4;++r)
        slot[(mi*16 + 4*g + r)*32 + ni*16 + l15] = aqk[mi][ni][r];
  #pragma unroll
  for (int mi=0;mi<2;++mi)
    #pragma unroll
    for (int r=0;r<4;++r)
      if (l15 == 4*g + r){
        slot[1024 + mi*16 + l15] = aqq[mi][r];
        slot[1056 + mi*16 + l15] = akk[mi][r];
      }
}

// -------- reduce partials, l2-normalize, temperature, softmax, fold +I -> A[48][32][32]
__global__ __launch_bounds__(256) void k_sm(
    const float* __restrict__ P, const float* __restrict__ temp, float* __restrict__ A)
{
  __shared__ float red[1088];
  const int bh = blockIdx.x, t = threadIdx.x;
  const float* base = P + (size_t)bh*64*1088;
  for (int i=t; i<1088; i+=256){
    float s = 0.f;
    for (int sl=0; sl<64; ++sl) s += base[(size_t)sl*1088 + i];
    red[i] = s;
  }
  __syncthreads();
  const int c = t >> 3, dq = t & 7;
  const float qn = fmaxf(sqrtf(red[1024+c]), 1e-12f);
  const float tp = temp[bh % 6];
  float v[4];
  #pragma unroll
  for (int r=0;r<4;++r){
    const int d = dq*4 + r;
    const float kn = fmaxf(sqrtf(red[1056+d]), 1e-12f);
    v[r] = red[c*32+d] / (qn*kn) * tp;
  }
  float mx = fmaxf(fmaxf(v[0],v[1]), fmaxf(v[2],v[3]));
  mx = fmaxf(mx, __shfl_xor(mx,1));
  mx = fmaxf(mx, __shfl_xor(mx,2));
  mx = fmaxf(mx, __shfl_xor(mx,4));
  float e[4]; float sum = 0.f;
  #pragma unroll
  for (int r=0;r<4;++r){ e[r] = __expf(v[r]-mx); sum += e[r]; }
  sum += __shfl_xor(sum,1); sum += __shfl_xor(sum,2); sum += __shfl_xor(sum,4);
  const float inv = 1.f/sum;
  #pragma unroll
  for (int r=0;r<4;++r){
    const int d = dq*4 + r;
    A[(size_t)bh*1024 + c*32 + d] = e[r]*inv + ((c == d) ? 1.f : 0.f);
  }
}

#define R32(M) M(0) M(1) M(2) M(3) M(4) M(5) M(6) M(7) M(8) M(9) M(10) M(11) M(12) M(13) M(14) M(15) \
               M(16) M(17) M(18) M(19) M(20) M(21) M(22) M(23) M(24) M(25) M(26) M(27) M(28) M(29) M(30) M(31)

// swizzled stage index: [ch][lr][w], 16B groups XORed by row to break bank alignment
__device__ __forceinline__ int sidx(int ch, int lr, int w){
  return ch*512 + lr*128 + (((w >> 3) ^ (lr & 3)) << 3) + (w & 7);
}

// -------- fused: V = dw3x3(Sv), then out = (A+I)V + x.
// grid (96, 32): tens = bx&1, bh = bx>>1, y = 4-row tile. block 256, 32 KB LDS, 5 blocks/CU.
__global__ __launch_bounds__(256, 5) void k_out(
    const float* __restrict__ A, const unsigned short* __restrict__ Sv,
    const float* __restrict__ hsi, const float* __restrict__ lidar,
    const float* __restrict__ hdw, const float* __restrict__ ldw,
    const float* __restrict__ hdb, const float* __restrict__ ldb,
    float* __restrict__ outh, float* __restrict__ outl)
{
  const int tens = blockIdx.x & 1;
  const int bh   = blockIdx.x >> 1;     // 0..47
  const int y    = blockIdx.y;          // 0..31, rows 4y..4y+3
  const int b = bh/6, hd = bh%6;
  const int t = threadIdx.x;

  __shared__ __align__(16) unsigned short lds[16384];  // 32 KB, stage then V overlay

  const unsigned short* Sp = Sv + ((size_t)(tens*8 + b)*192 + hd*32)*16384;

  // phase 1: stage interior rows 4y..4y+3 (no halo), swizzled
  #pragma unroll
  for (int i=0;i<8;++i){
    const int seg = i*256 + t;        // 0..2047
    const int ch  = seg >> 6;
    const int rem = seg & 63;
    const int row = rem >> 4;
    const int w16 = rem & 15;
    const v8s val = *(const v8s*)(Sp + (size_t)ch*16384 + (4*y+row)*128 + w16*8);
    *(v8s*)&lds[ch*512 + row*128 + ((w16 ^ (row&3))<<3)] = val;
  }
  __syncthreads();

  // phase 2: dw 3x3. thread: cg = t>>6 (8 ch), pg = t&63 (8 px). halo rows from global.
  const int cg = t >> 6;
  const int pg = t & 63;
  const int rr = pg >> 4;               // tile row 0..3
  const int w0 = (pg & 15) * 8;
  const float* dwW = (tens ? ldw : hdw) + (192 + hd*32 + cg*8)*9;
  const float* dwB = (tens ? ldb : hdb) + 192 + hd*32 + cg*8;

  v8s vpk[8];
  #pragma unroll
  for (int cc=0; cc<8; ++cc){
    const int ch = cg*8 + cc;
    float a9[3][10];
    #pragma unroll
    for (int dy=0; dy<3; ++dy){
      const int lr = rr - 1 + dy;
      if (lr >= 0 && lr < 4){
        const v8s m = *(const v8s*)&lds[sidx(ch, lr, w0)];
        #pragma unroll
        for (int j=0;j<8;++j) a9[dy][j+1] = bf2f((unsigned short)m[j]);
        a9[dy][0] = (w0 > 0)   ? bf2f(lds[sidx(ch, lr, w0-1)]) : 0.f;
        a9[dy][9] = (w0 < 120) ? bf2f(lds[sidx(ch, lr, w0+8)]) : 0.f;
      } else {
        const int gr = 4*y + lr;        // 4y-1 or 4y+4
        if (gr >= 0 && gr < 128){
          const unsigned short* rp = Sp + (size_t)ch*16384 + gr*128;
          const v8s m = *(const v8s*)(rp + w0);
          #pragma unroll
          for (int j=0;j<8;++j) a9[dy][j+1] = bf2f((unsigned short)m[j]);
          a9[dy][0] = (w0 > 0)   ? bf2f(rp[w0-1]) : 0.f;
          a9[dy][9] = (w0 < 120) ? bf2f(rp[w0+8]) : 0.f;
        } else {
          #pragma unroll
          for (int j=0;j<10;++j) a9[dy][j] = 0.f;
        }
      }
    }
    const float* wp = dwW + cc*9;
    const float k00=wp[0],k01=wp[1],k02=wp[2],k10=wp[3],k11=wp[4],k12=wp[5],k20=wp[6],k21=wp[7],k22=wp[8];
    const float bs = dwB[cc];
    v8s o;
    #pragma unroll
    for (int j=0;j<8;++j){
      float a = bs
        + a9[0][j]*k00 + a9[0][j+1]*k01 + a9[0][j+2]*k02
        + a9[1][j]*k10 + a9[1][j+1]*k11 + a9[1][j+2]*k12
        + a9[2][j]*k20 + a9[2][j+1]*k21 + a9[2][j+2]*k22;
      o[j] = (short)f2bf(a);
    }
    vpk[cc] = o;
  }
  __syncthreads();   // all stage reads done

  // phase 3: write V bf16 over the stage area as [32][512]
  #pragma unroll
  for (int cc=0; cc<8; ++cc)
    *(v8s*)&lds[(cg*8 + cc)*512 + pg*8] = vpk[cc];
  __syncthreads();

  // phase 4: epilogue, 2 pixels per thread
  const int sl = 2*t;
  const int s  = y*512 + sl;
  const float* Ab = A + (size_t)bh*1024;
  const float* X = (tens ? lidar : hsi) + ((size_t)b*192 + hd*32)*16384 + s;
  float* O = (tens ? outl : outh) + ((size_t)b*192 + hd*32)*16384 + s;

  v32f vx, vy;
#define LD_V(dd) { const unsigned u = *(const unsigned*)&lds[(dd)*512 + sl]; \
                   vx[dd] = bf2f((unsigned short)u); vy[dd] = bf2f((unsigned short)(u >> 16)); }
  R32(LD_V)
#undef LD_V

  #pragma unroll 4
  for (int c=0; c<32; ++c){
    const float* Arow = Ab + c*32;
    const float2 x = *(const float2*)(X + (size_t)c*16384);
    float ax = x.x, ay = x.y;
#define FMA_D(dd) { const float a = Arow[dd]; ax += a*vx[dd]; ay += a*vy[dd]; }
    R32(FMA_D)
#undef FMA_D
    float2 o; o.x = ax; o.y = ay;
    *(float2*)(O + (size_t)c*16384) = o;
  }
}

// -------- convert both 1x1 weights to bf16 in MFMA fragment order:
// Wfrag[tens][wid(8)][ks(6)][mi(3)][lane(64)][8]
__global__ __launch_bounds__(256) void k_wcvt(
    const float* __restrict__ a, const float* __restrict__ b, unsigned short* __restrict__ o)
{
  const int i = blockIdx.x*256 + threadIdx.x;
  if (i >= 147456) return;
  const int jj = i & 7;
  const int l  = (i >> 3) & 63;
  const int rest = i >> 9;          // ((tens*8+wid)*6+ks)*3+mi, 0..287
  const int mi = rest % 3;
  const int ks = (rest / 3) % 6;
  const int q  = rest / 18;         // tens*8 + wid
  const int wid = q & 7, tens = q >> 3;
  const int row = wid*48 + mi*16 + (l & 15);
  const int col = ks*32 + (l >> 4)*8 + jj;
  const float* src = tens ? b : a;
  o[i] = f2bf(src[row*192 + col]);
}

extern "C" void kernel_launch(void* const* d_in, const int* in_sizes, int n_in,
                              void* d_out, int out_size, void* d_ws, size_t ws_size,
                              hipStream_t stream) {
  const float* hsi   = (const float*)d_in[0];
  const float* lidar = (const float*)d_in[1];
  const float* hqw   = (const float*)d_in[2];
  const float* hqb   = (const float*)d_in[3];
  const float* lkw   = (const float*)d_in[4];
  const float* lkb   = (const float*)d_in[5];
  const float* hdw   = (const float*)d_in[6];
  const float* hdb   = (const float*)d_in[7];
  const float* ldw   = (const float*)d_in[8];
  const float* ldb   = (const float*)d_in[9];
  const float* temp  = (const float*)d_in[10];

  char* ws = (char*)d_ws;
  unsigned short* Sv  = (unsigned short*)(ws);                 // 100663296 B (V half of conv out)
  unsigned short* Qh  = (unsigned short*)(ws + 100663296);     // 50331648 B
  unsigned short* Kl  = (unsigned short*)(ws + 150994944);     // 50331648 B
  unsigned short* Wbf = (unsigned short*)(ws + 201326592);     // 294912 B
  float* P            = (float*)(ws + 201621504);              // 13369344 B
  float* A            = (float*)(ws + 214990848);              // 196608 B

  float* outh = (float*)d_out;
  float* outl = outh + 25165824;
  // Q/K half of conv output staged inside d_out (dead before k_out writes)
  unsigned short* Sqk = (unsigned short*)d_out;                // 100663296 B

  k_wcvt<<<576, 256, 0, stream>>>(hqw, lkw, Wbf);
  k_conv1x1<<<4096, 512, 0, stream>>>(hsi, lidar, Wbf, hqb, lkb, Sqk, Sv);
  k_dw<<<24576, 256, 0, stream>>>(Sqk, hdw, ldw, hdb, ldb, Qh, Kl);
  k_qk<<<dim3(48, 16), 256, 0, stream>>>(Qh, Kl, P);
  k_sm<<<48, 256, 0, stream>>>(P, temp, A);
  k_out<<<dim3(96, 32), 256, 0, stream>>>(A, Sv, hsi, lidar, hdw, ldw, hdb, ldb, outh, outl);
}

// Round 7
// 418.430 us; speedup vs baseline: 3.3658x; 3.3658x over previous
//
#include <hip/hip_runtime.h>

typedef short v8s __attribute__((ext_vector_type(8)));
typedef float v4f __attribute__((ext_vector_type(4)));
typedef unsigned v4u __attribute__((ext_vector_type(4)));

__device__ __forceinline__ unsigned short f2bf(float f){
  unsigned u = __builtin_bit_cast(unsigned, f);
  return (unsigned short)((u + 0x7fffu + ((u>>16)&1u)) >> 16);
}
__device__ __forceinline__ float bf2f(unsigned short s){
  return __builtin_bit_cast(float, ((unsigned)s) << 16);
}

// -------- conv1x1 as MFMA GEMM, both tensors in one launch.
// Q/K out-channels (0..191) -> Sqk (in d_out); V out-channels (192..383) -> Sv (in ws).
// grid 4096 (2 tensors x 2048 n-tiles of 64), block 512 (8 waves, m-stripes of 48).
__global__ __launch_bounds__(512) void k_conv1x1(
    const float* __restrict__ hsi, const float* __restrict__ lidar,
    const unsigned short* __restrict__ Wfrag, const float* __restrict__ hqb,
    const float* __restrict__ lkb, unsigned short* __restrict__ Sqk,
    unsigned short* __restrict__ Sv)
{
  const int bx   = blockIdx.x;
  const int tens = bx >> 11;
  const int nt   = bx & 2047;
  const int b    = nt >> 8;
  const int hw0  = (nt & 255) << 6;
  const float* X = (tens ? lidar : hsi) + ((size_t)b * 192) * 16384 + hw0;
  const float* bias = tens ? lkb : hqb;

  __shared__ unsigned short Xt[64][200];   // transposed bf16 X tile, padded

  {
    const int c4   = (threadIdx.x & 15) * 4;
    const int krow = threadIdx.x >> 4;     // 0..31
    const float* xb2 = X + c4;
    float4 f[6];
    #pragma unroll
    for (int j = 0; j < 3; ++j){
      const int k = krow*2 + j*64;
      f[2*j]   = *(const float4*)(xb2 + (size_t)k * 16384);
      f[2*j+1] = *(const float4*)(xb2 + (size_t)(k+1) * 16384);
    }
    #pragma unroll
    for (int j = 0; j < 3; ++j){
      const int k = krow*2 + j*64;
      #pragma unroll
      for (int i2 = 0; i2 < 4; ++i2){
        const unsigned lo = f2bf(((const float*)&f[2*j])[i2]);
        const unsigned hi = f2bf(((const float*)&f[2*j+1])[i2]);
        *(unsigned*)&Xt[c4 + i2][k] = lo | (hi << 16);
      }
    }
  }
  __syncthreads();

  const int lane = threadIdx.x & 63;
  const int wid  = threadIdx.x >> 6;      // 0..7
  const int l15  = lane & 15;
  const int g    = lane >> 4;
  const int mstripe = wid * 48;
  const unsigned short* wb = Wfrag + ((size_t)(tens*8 + wid) * 18) * 512 + (lane << 3);

  v4f acc[3][4];
  #pragma unroll
  for (int i=0;i<3;i++)
    #pragma unroll
    for (int j=0;j<4;j++)
      acc[i][j] = (v4f){0.f,0.f,0.f,0.f};

  #pragma unroll
  for (int ks=0; ks<6; ++ks){
    const int k0 = ks*32;
    v8s af[3];
    #pragma unroll
    for (int mi=0; mi<3; ++mi)
      af[mi] = *(const v8s*)(wb + (size_t)(ks*3 + mi) * 512);
    #pragma unroll
    for (int ni=0; ni<4; ++ni){
      const v8s bfr = *(const v8s*)&Xt[ni*16 + l15][k0 + 8*g];
      #pragma unroll
      for (int mi=0; mi<3; ++mi)
        acc[mi][ni] = __builtin_amdgcn_mfma_f32_16x16x32_bf16(af[mi], bfr, acc[mi][ni], 0, 0, 0);
    }
  }

  unsigned short* outp;
  int cb;
  if (mstripe < 192){
    outp = Sqk + ((size_t)(tens*8 + b) * 192) * 16384 + hw0;
    cb = mstripe;
  } else {
    outp = Sv + ((size_t)(tens*8 + b) * 192) * 16384 + hw0;
    cb = mstripe - 192;
  }
  #pragma unroll
  for (int mi=0; mi<3; ++mi){
    #pragma unroll
    for (int r=0; r<4; ++r){
      const int co = mi*16 + 4*g + r;
      const float bs = bias[mstripe + co];
      #pragma unroll
      for (int ni=0; ni<4; ++ni)
        outp[(size_t)(cb + co)*16384 + ni*16 + l15] = f2bf(acc[mi][ni][r] + bs);
    }
  }
}

// -------- depthwise 3x3 SAME, Q/K halves only. one thread = 8 outputs along w.
__global__ __launch_bounds__(256) void k_dw(
    const unsigned short* __restrict__ Sqk, const float* __restrict__ hdw,
    const float* __restrict__ ldw, const float* __restrict__ hdb,
    const float* __restrict__ ldb, unsigned short* __restrict__ Qh,
    unsigned short* __restrict__ Kl)
{
  const int idx = blockIdx.x*256 + threadIdx.x;
  const int w8 = idx & 15;
  const int h  = (idx >> 4) & 127;
  const int pc = idx >> 11;            // 0..3071
  const int tens = (pc >= 1536);
  const int lc = pc - tens*1536;       // b*192 + c
  const int c  = lc % 192;
  const unsigned short* in = Sqk + (size_t)pc*16384;

  float r[3][10];
  #pragma unroll
  for (int dy=0; dy<3; ++dy){
    const int hh = h + dy - 1;
    if (hh >= 0 && hh < 128){
      const unsigned short* row = in + hh*128 + w8*8;
      const v8s m = *(const v8s*)row;
      #pragma unroll
      for (int i=0;i<8;++i) r[dy][i+1] = bf2f((unsigned short)m[i]);
      r[dy][0] = (w8 > 0)  ? bf2f(row[-1]) : 0.f;
      r[dy][9] = (w8 < 15) ? bf2f(row[8])  : 0.f;
    } else {
      #pragma unroll
      for (int i=0;i<10;++i) r[dy][i] = 0.f;
    }
  }
  const float* wp = (tens ? ldw : hdw) + c*9;
  const float k00=wp[0],k01=wp[1],k02=wp[2],k10=wp[3],k11=wp[4],k12=wp[5],k20=wp[6],k21=wp[7],k22=wp[8];
  const float bs = (tens ? ldb : hdb)[c];
  v8s out;
  #pragma unroll
  for (int j=0;j<8;++j){
    float a = bs
      + r[0][j]*k00 + r[0][j+1]*k01 + r[0][j+2]*k02
      + r[1][j]*k10 + r[1][j+1]*k11 + r[1][j+2]*k12
      + r[2][j]*k20 + r[2][j+1]*k21 + r[2][j+2]*k22;
    out[j] = (short)f2bf(a);
  }
  *(v8s*)((tens ? Kl : Qh) + (size_t)lc*16384 + h*128 + w8*8) = out;
}

// -------- QK^T partials + row sumsq via Gram MFMAs.
// grid (48, 16), block 256 (4 waves, 256 s each). P: [48][64][1088]
__global__ __launch_bounds__(256) void k_qk(
    const unsigned short* __restrict__ Q, const unsigned short* __restrict__ K,
    float* __restrict__ P)
{
  const int bh = blockIdx.x, split = blockIdx.y;
  const int lane = threadIdx.x & 63, wid = threadIdx.x >> 6;
  const int l15 = lane & 15, g = lane >> 4;
  const int b = bh/6, hd = bh%6;
  const unsigned short* qb = Q + ((size_t)b*192 + hd*32)*16384;
  const unsigned short* kb = K + ((size_t)b*192 + hd*32)*16384;
  const int s0 = (split*4 + wid)*256;

  v4f aqk[2][2], aqq[2], akk[2];
  #pragma unroll
  for (int i=0;i<2;i++){
    aqq[i] = (v4f){0.f,0.f,0.f,0.f};
    akk[i] = (v4f){0.f,0.f,0.f,0.f};
    #pragma unroll
    for (int j=0;j<2;j++) aqk[i][j] = (v4f){0.f,0.f,0.f,0.f};
  }

  #pragma unroll
  for (int ks=0; ks<8; ++ks){
    const int s = s0 + ks*32 + 8*g;
    v8s qf[2], kf[2];
    #pragma unroll
    for (int mi=0;mi<2;++mi) qf[mi] = *(const v8s*)(qb + (size_t)(mi*16 + l15)*16384 + s);
    #pragma unroll
    for (int ni=0;ni<2;++ni) kf[ni] = *(const v8s*)(kb + (size_t)(ni*16 + l15)*16384 + s);
    #pragma unroll
    for (int mi=0;mi<2;++mi)
      #pragma unroll
      for (int ni=0;ni<2;++ni)
        aqk[mi][ni] = __builtin_amdgcn_mfma_f32_16x16x32_bf16(qf[mi], kf[ni], aqk[mi][ni],0,0,0);
    #pragma unroll
    for (int mi=0;mi<2;++mi){
      aqq[mi] = __builtin_amdgcn_mfma_f32_16x16x32_bf16(qf[mi], qf[mi], aqq[mi],0,0,0);
      akk[mi] = __builtin_amdgcn_mfma_f32_16x16x32_bf16(kf[mi], kf[mi], akk[mi],0,0,0);
    }
  }
  float* slot = P + ((size_t)bh*64 + split*4 + wid)*1088;
  #pragma unroll
  for (int mi=0;mi<2;++mi)
    #pragma unroll
    for (int ni=0;ni<2;++ni)
      #pragma unroll
      for (int r=0;r<4;++r)
        slot[(mi*16 + 4*g + r)*32 + ni*16 + l15] = aqk[mi][ni][r];
  #pragma unroll
  for (int mi=0;mi<2;++mi)
    #pragma unroll
    for (int r=0;r<4;++r)
      if (l15 == 4*g + r){
        slot[1024 + mi*16 + l15] = aqq[mi][r];
        slot[1056 + mi*16 + l15] = akk[mi][r];
      }
}

// -------- reduce partials, l2-normalize, temperature, softmax, fold +I -> A16 bf16 [48][32][32]
__global__ __launch_bounds__(256) void k_sm(
    const float* __restrict__ P, const float* __restrict__ temp, unsigned short* __restrict__ A16)
{
  __shared__ float red[1088];
  const int bh = blockIdx.x, t = threadIdx.x;
  const float* base = P + (size_t)bh*64*1088;
  for (int i=t; i<1088; i+=256){
    float s = 0.f;
    for (int sl=0; sl<64; ++sl) s += base[(size_t)sl*1088 + i];
    red[i] = s;
  }
  __syncthreads();
  const int c = t >> 3, dq = t & 7;
  const float qn = fmaxf(sqrtf(red[1024+c]), 1e-12f);
  const float tp = temp[bh % 6];
  float v[4];
  #pragma unroll
  for (int r=0;r<4;++r){
    const int d = dq*4 + r;
    const float kn = fmaxf(sqrtf(red[1056+d]), 1e-12f);
    v[r] = red[c*32+d] / (qn*kn) * tp;
  }
  float mx = fmaxf(fmaxf(v[0],v[1]), fmaxf(v[2],v[3]));
  mx = fmaxf(mx, __shfl_xor(mx,1));
  mx = fmaxf(mx, __shfl_xor(mx,2));
  mx = fmaxf(mx, __shfl_xor(mx,4));
  float e[4]; float sum = 0.f;
  #pragma unroll
  for (int r=0;r<4;++r){ e[r] = __expf(v[r]-mx); sum += e[r]; }
  sum += __shfl_xor(sum,1); sum += __shfl_xor(sum,2); sum += __shfl_xor(sum,4);
  const float inv = 1.f/sum;
  #pragma unroll
  for (int r=0;r<4;++r){
    const int d = dq*4 + r;
    A16[(size_t)bh*1024 + c*32 + d] = f2bf(e[r]*inv + ((c == d) ? 1.f : 0.f));
  }
}

// swizzled stage index: [ch][lr][w], 16B groups XORed by row to break bank alignment
__device__ __forceinline__ int sidx(int ch, int lr, int w){
  return ch*512 + lr*128 + (((w >> 3) ^ (lr & 3)) << 3) + (w & 7);
}

// -------- fused: V = dw3x3(Sv) in LDS, then out = (A+I)@V + x via MFMA.
// grid (96, 32): tens = bx&1, bh = bx>>1, y = 4-row tile. block 256 (4 waves), 32 KB LDS.
__global__ __launch_bounds__(256) void k_out(
    const unsigned short* __restrict__ A16, const unsigned short* __restrict__ Sv,
    const float* __restrict__ hsi, const float* __restrict__ lidar,
    const float* __restrict__ hdw, const float* __restrict__ ldw,
    const float* __restrict__ hdb, const float* __restrict__ ldb,
    float* __restrict__ outh, float* __restrict__ outl)
{
  const int tens = blockIdx.x & 1;
  const int bh   = blockIdx.x >> 1;     // 0..47
  const int y    = blockIdx.y;          // 0..31, rows 4y..4y+3
  const int b = bh/6, hd = bh%6;
  const int t = threadIdx.x;

  __shared__ __align__(16) unsigned short lds[16384];  // 32 KB: stage, then Vt overlay

  const unsigned short* Sp = Sv + ((size_t)(tens*8 + b)*192 + hd*32)*16384;

  // phase 1: stage interior rows 4y..4y+3 (no halo), swizzled
  #pragma unroll
  for (int i=0;i<8;++i){
    const int seg = i*256 + t;        // 0..2047
    const int ch  = seg >> 6;
    const int rem = seg & 63;
    const int row = rem >> 4;
    const int w16 = rem & 15;
    const v8s val = *(const v8s*)(Sp + (size_t)ch*16384 + (4*y+row)*128 + w16*8);
    *(v8s*)&lds[ch*512 + row*128 + ((w16 ^ (row&3))<<3)] = val;
  }
  __syncthreads();

  // phase 2: dw 3x3. thread: cg = t>>6 (8 ch), pg = t&63 (8 px). halo rows from global.
  const int cg = t >> 6;                // wave id
  const int pg = t & 63;
  const int rr = pg >> 4;               // tile row 0..3
  const int w0 = (pg & 15) * 8;
  const float* dwW = (tens ? ldw : hdw) + (192 + hd*32 + cg*8)*9;
  const float* dwB = (tens ? ldb : hdb) + 192 + hd*32 + cg*8;

  v8s vpk[8];
  #pragma unroll
  for (int cc=0; cc<8; ++cc){
    const int ch = cg*8 + cc;
    float a9[3][10];
    #pragma unroll
    for (int dy=0; dy<3; ++dy){
      const int lr = rr - 1 + dy;
      if (lr >= 0 && lr < 4){
        const v8s m = *(const v8s*)&lds[sidx(ch, lr, w0)];
        #pragma unroll
        for (int j=0;j<8;++j) a9[dy][j+1] = bf2f((unsigned short)m[j]);
        a9[dy][0] = (w0 > 0)   ? bf2f(lds[sidx(ch, lr, w0-1)]) : 0.f;
        a9[dy][9] = (w0 < 120) ? bf2f(lds[sidx(ch, lr, w0+8)]) : 0.f;
      } else {
        const int gr = 4*y + lr;        // 4y-1 or 4y+4
        if (gr >= 0 && gr < 128){
          const unsigned short* rp = Sp + (size_t)ch*16384 + gr*128;
          const v8s m = *(const v8s*)(rp + w0);
          #pragma unroll
          for (int j=0;j<8;++j) a9[dy][j+1] = bf2f((unsigned short)m[j]);
          a9[dy][0] = (w0 > 0)   ? bf2f(rp[w0-1]) : 0.f;
          a9[dy][9] = (w0 < 120) ? bf2f(rp[w0+8]) : 0.f;
        } else {
          #pragma unroll
          for (int j=0;j<10;++j) a9[dy][j] = 0.f;
        }
      }
    }
    const float* wp = dwW + cc*9;
    const float k00=wp[0],k01=wp[1],k02=wp[2],k10=wp[3],k11=wp[4],k12=wp[5],k20=wp[6],k21=wp[7],k22=wp[8];
    const float bs = dwB[cc];
    v8s o;
    #pragma unroll
    for (int j=0;j<8;++j){
      float a = bs
        + a9[0][j]*k00 + a9[0][j+1]*k01 + a9[0][j+2]*k02
        + a9[1][j]*k10 + a9[1][j+1]*k11 + a9[1][j+2]*k12
        + a9[2][j]*k20 + a9[2][j+1]*k21 + a9[2][j+2]*k22;
      o[j] = (short)f2bf(a);
    }
    vpk[cc] = o;
  }
  __syncthreads();   // all stage reads done

  // phase 3: write V into subtiled pair-interleaved layout:
  // element (d, sl) at (sl>>4)*512 + (d>>1)*32 + (sl&15)*2 + (d&1)
  {
    const int tile = rr*8 + (w0 >> 4);
    const int colb = (w0 & 8) * 2;      // 0 or 16 shorts
    #pragma unroll
    for (int p=0; p<4; ++p){
      const v8s o0 = __builtin_shufflevector(vpk[2*p], vpk[2*p+1], 0,8,1,9,2,10,3,11);
      const v8s o1 = __builtin_shufflevector(vpk[2*p], vpk[2*p+1], 4,12,5,13,6,14,7,15);
      unsigned short* dst = &lds[tile*512 + (cg*4 + p)*32 + colb];
      *(v8s*)(dst)     = o0;
      *(v8s*)(dst + 8) = o1;
    }
  }
  __syncthreads();

  // phase 4: MFMA epilogue. wave cg handles tiles cg*8..cg*8+7 (128 px).
  const int lane = t & 63;
  const int l15 = lane & 15, g = lane >> 4;
  const float* Xb = (tens ? lidar : hsi) + ((size_t)b*192 + hd*32)*16384;
  float* Ob = (tens ? outl : outh) + ((size_t)b*192 + hd*32)*16384;

  v8s afr[2];
  afr[0] = *(const v8s*)(A16 + (size_t)bh*1024 + (size_t)l15*32 + 8*g);
  afr[1] = *(const v8s*)(A16 + (size_t)bh*1024 + (size_t)(16 + l15)*32 + 8*g);

  #pragma unroll
  for (int nt=0; nt<8; ++nt){
    const int tile = cg*8 + nt;
    const int s = y*512 + tile*16 + l15;
    v4u up;
    #pragma unroll
    for (int p=0;p<4;++p)
      up[p] = *(const unsigned*)&lds[tile*512 + (4*g + p)*32 + l15*2];
    const v8s bfr = __builtin_bit_cast(v8s, up);
    #pragma unroll
    for (int mi=0; mi<2; ++mi){
      v4f cin;
      #pragma unroll
      for (int r=0;r<4;++r)
        cin[r] = Xb[(size_t)(mi*16 + 4*g + r)*16384 + s];
      const v4f dres = __builtin_amdgcn_mfma_f32_16x16x32_bf16(afr[mi], bfr, cin, 0, 0, 0);
      #pragma unroll
      for (int r=0;r<4;++r)
        Ob[(size_t)(mi*16 + 4*g + r)*16384 + s] = dres[r];
    }
  }
}

// -------- convert both 1x1 weights to bf16 in MFMA fragment order:
// Wfrag[tens][wid(8)][ks(6)][mi(3)][lane(64)][8]
__global__ __launch_bounds__(256) void k_wcvt(
    const float* __restrict__ a, const float* __restrict__ b, unsigned short* __restrict__ o)
{
  const int i = blockIdx.x*256 + threadIdx.x;
  if (i >= 147456) return;
  const int jj = i & 7;
  const int l  = (i >> 3) & 63;
  const int rest = i >> 9;          // ((tens*8+wid)*6+ks)*3+mi, 0..287
  const int mi = rest % 3;
  const int ks = (rest / 3) % 6;
  const int q  = rest / 18;         // tens*8 + wid
  const int wid = q & 7, tens = q >> 3;
  const int row = wid*48 + mi*16 + (l & 15);
  const int col = ks*32 + (l >> 4)*8 + jj;
  const float* src = tens ? b : a;
  o[i] = f2bf(src[row*192 + col]);
}

extern "C" void kernel_launch(void* const* d_in, const int* in_sizes, int n_in,
                              void* d_out, int out_size, void* d_ws, size_t ws_size,
                              hipStream_t stream) {
  const float* hsi   = (const float*)d_in[0];
  const float* lidar = (const float*)d_in[1];
  const float* hqw   = (const float*)d_in[2];
  const float* hqb   = (const float*)d_in[3];
  const float* lkw   = (const float*)d_in[4];
  const float* lkb   = (const float*)d_in[5];
  const float* hdw   = (const float*)d_in[6];
  const float* hdb   = (const float*)d_in[7];
  const float* ldw   = (const float*)d_in[8];
  const float* ldb   = (const float*)d_in[9];
  const float* temp  = (const float*)d_in[10];

  char* ws = (char*)d_ws;
  unsigned short* Sv  = (unsigned short*)(ws);                 // 100663296 B (V half of conv out)
  unsigned short* Qh  = (unsigned short*)(ws + 100663296);     // 50331648 B
  unsigned short* Kl  = (unsigned short*)(ws + 150994944);     // 50331648 B
  unsigned short* Wbf = (unsigned short*)(ws + 201326592);     // 294912 B
  float* P            = (float*)(ws + 201621504);              // 13369344 B
  unsigned short* A16 = (unsigned short*)(ws + 214990848);     // 98304 B

  float* outh = (float*)d_out;
  float* outl = outh + 25165824;
  // Q/K half of conv output staged inside d_out (dead before k_out writes)
  unsigned short* Sqk = (unsigned short*)d_out;                // 100663296 B

  k_wcvt<<<576, 256, 0, stream>>>(hqw, lkw, Wbf);
  k_conv1x1<<<4096, 512, 0, stream>>>(hsi, lidar, Wbf, hqb, lkb, Sqk, Sv);
  k_dw<<<24576, 256, 0, stream>>>(Sqk, hdw, ldw, hdb, ldb, Qh, Kl);
  k_qk<<<dim3(48, 16), 256, 0, stream>>>(Qh, Kl, P);
  k_sm<<<48, 256, 0, stream>>>(P, temp, A16);
  k_out<<<dim3(96, 32), 256, 0, stream>>>(A16, Sv, hsi, lidar, hdw, ldw, hdb, ldb, outh, outl);
}